// Round 5
// baseline (117.509 us; speedup 1.0000x reference)
//
#include <hip/hip_runtime.h>

// SpectralConv2d: B=2,L=8,C=64,H=64,W=33, M1=M2=16
// Round 5: DIAGNOSTIC build. Base = round-1 kernel (proven best, 93.4us)
// with the c-loop executed REPS=4 times (accumulating; stores scaled by
// 1/REPS, bit-error ~1e-5 << 1.56e-2 tolerance). Purpose: push the compute
// kernel above the ~43us harness fills so rocprof's top-5 shows its
// VALUBusy / FETCH_SIZE / SQ_LDS_BANK_CONFLICT / VGPR row, discriminating
// request-throughput vs VALU-issue vs LDS-conflict as the real bottleneck.
// The marginal cost of 3 extra c-loops also measures the c-loop phase
// directly: dur ~= 24 + 3*c_loop_us.

constexpr int Cc    = 64;
constexpr int Ww    = 33;
constexpr int HW    = 64 * Ww;        // 2112
constexpr int PLANE = Cc * HW;        // 135168
constexpr int TOT   = 16 * PLANE;     // 2162688 (elements in real half)
constexpr int WSTR  = Cc * 16 * 16;   // 16384: o-stride in weight tensor
constexpr int REPS  = 4;              // diagnostic work multiplier

__global__ __launch_bounds__(256) void spectral_fused_kernel(
    const float* __restrict__ xr, const float* __restrict__ xi,
    const float* __restrict__ wr1, const float* __restrict__ wi1,
    const float* __restrict__ wr2, const float* __restrict__ wi2,
    float* __restrict__ out)
{
    const int bid = blockIdx.x;
    const int t   = threadIdx.x;

    if (bid < 512) {
        // ---- compute blocks: oq(4) | blq(4) | xrow(16) | corner(2) ----
        const int oq     = bid & 3;
        const int blq    = (bid >> 2) & 3;
        const int xrow   = (bid >> 4) & 15;
        const int corner = bid >> 8;
        const int xin    = corner ? (48 + xrow) : xrow;
        const float* wr  = corner ? wr2 : wr1;
        const float* wi  = corner ? wi2 : wi1;

        // [r(2)][c(64)][blj(4)][y(16)] floats = 8192 floats = 32 KB
        __shared__ __align__(16) float xs[8192];

        // ---- stage x slice: coalesced scalar loads ----
        {
            const int y  = t & 15;
            const int wb = (t >> 4) & 3;
            const int cg = t >> 6;
            const int src_base = (blq * 4 + wb) * PLANE + xin * Ww + y;
            #pragma unroll
            for (int k = 0; k < 32; ++k) {
                const int r = k >> 4;
                const int c = ((k & 15) << 2) | cg;
                const float* src = (r ? xi : xr) + (size_t)src_base + c * HW;
                xs[r * 4096 + c * 64 + wb * 16 + y] = *src;
            }
        }
        __syncthreads();

        // ---- compute: thread = (yq, blj, ol) ----
        const int yq  = t & 3;
        const int blj = (t >> 2) & 3;
        const int ol  = t >> 4;
        const int o   = oq * 16 + ol;
        const int bl  = blq * 4 + blj;

        const float* wrp = wr + o * WSTR + xrow * 16 + yq * 4;
        const float* wip = wi + o * WSTR + xrow * 16 + yq * 4;
        const float4* xsr = reinterpret_cast<const float4*>(xs) + blj * 4 + yq;
        const float4* xsi = xsr + 1024;

        float4 ar = make_float4(0.f, 0.f, 0.f, 0.f);
        float4 ai = make_float4(0.f, 0.f, 0.f, 0.f);

        #pragma unroll 1
        for (int rep = 0; rep < REPS; ++rep) {
            #pragma unroll 8
            for (int c = 0; c < Cc; ++c) {
                const float4 wre = *reinterpret_cast<const float4*>(wrp + c * 256);
                const float4 wim = *reinterpret_cast<const float4*>(wip + c * 256);
                const float4 a   = xsr[c * 16];
                const float4 b   = xsi[c * 16];
                ar.x = fmaf(a.x, wre.x, ar.x); ar.x = fmaf(-b.x, wim.x, ar.x);
                ai.x = fmaf(a.x, wim.x, ai.x); ai.x = fmaf( b.x, wre.x, ai.x);
                ar.y = fmaf(a.y, wre.y, ar.y); ar.y = fmaf(-b.y, wim.y, ar.y);
                ai.y = fmaf(a.y, wim.y, ai.y); ai.y = fmaf( b.y, wre.y, ai.y);
                ar.z = fmaf(a.z, wre.z, ar.z); ar.z = fmaf(-b.z, wim.z, ar.z);
                ai.z = fmaf(a.z, wim.z, ai.z); ai.z = fmaf( b.z, wre.z, ai.z);
                ar.w = fmaf(a.w, wre.w, ar.w); ar.w = fmaf(-b.w, wim.w, ar.w);
                ai.w = fmaf(a.w, wim.w, ai.w); ai.w = fmaf( b.w, wre.w, ai.w);
            }
        }

        constexpr float SCL = 1.0f / REPS;
        const size_t ob = (size_t)(bl * Cc + o) * HW + xin * Ww + yq * 4;
        out[ob + 0] = ar.x * SCL; out[ob + 1] = ar.y * SCL;
        out[ob + 2] = ar.z * SCL; out[ob + 3] = ar.w * SCL;
        out[TOT + ob + 0] = ai.x * SCL; out[TOT + ob + 1] = ai.y * SCL;
        out[TOT + ob + 2] = ai.z * SCL; out[TOT + ob + 3] = ai.w * SCL;

        // ---- zero y in [16,33) tails: 16 o x 4 bl x 17 y x 2 ri = 2176 ----
        #pragma unroll
        for (int q = 0; q < 9; ++q) {
            const int k = t + q * 256;
            if (k < 2176) {
                const int ri   = k >= 1088;
                const int rem  = ri ? (k - 1088) : k;
                const int ol_  = rem / 68;
                const int sub  = rem - ol_ * 68;
                const int blj_ = sub / 17;
                const int yy   = 16 + (sub - blj_ * 17);
                const size_t idx = (size_t)((blq * 4 + blj_) * Cc + oq * 16 + ol_) * HW
                                 + (size_t)xin * Ww + yy + (ri ? (size_t)TOT : 0);
                out[idx] = 0.f;
            }
        }
    } else {
        // ---- zero blocks: one per (ri, bl, o) plane, middle rows h in [16,48)
        const int p     = bid - 512;
        const int ri    = p >> 10;
        const int plane = p & 1023;
        float4* dst = (float4*)(out + (size_t)ri * TOT + (size_t)plane * HW + 528);
        const float4 z = make_float4(0.f, 0.f, 0.f, 0.f);
        dst[t] = z;
        if (t < 8) dst[256 + t] = z;
    }
}

extern "C" void kernel_launch(void* const* d_in, const int* in_sizes, int n_in,
                              void* d_out, int out_size, void* d_ws, size_t ws_size,
                              hipStream_t stream) {
    const float* xr  = (const float*)d_in[0];
    const float* xi  = (const float*)d_in[1];
    const float* wr1 = (const float*)d_in[2];
    const float* wi1 = (const float*)d_in[3];
    const float* wr2 = (const float*)d_in[4];
    const float* wi2 = (const float*)d_in[5];
    float* out = (float*)d_out;

    spectral_fused_kernel<<<2560, 256, 0, stream>>>(xr, xi, wr1, wi1, wr2, wi2, out);
}

// Round 6
// 94.482 us; speedup vs baseline: 1.2437x; 1.2437x over previous
//
#include <hip/hip_runtime.h>

// SpectralConv2d: B=2,L=8,C=64,H=64,W=33, M1=M2=16
// Round 6: TA-bound fix. Diagnosis (REPS=4 build): c-loop = 7.8us/pass,
// bound by vector-memory ADDRESS ISSUE on weight loads (~16cy per 64-lane
// dwordx4, 2/iter), not VALU (17%), not LDS conflicts (0), not HBM (15%).
// Fix: each thread now computes 2 o x 2 bl x 4 y (32 outputs) per c-iter:
//   4 weight loads + 4 LDS reads + 64 FMA  (was 2+2+16)
// -> weight-instr/FMA and LDS-instr/FMA both halve. TA ~3.4us, LDS ~2.6us.
// c is split 4-ways across waves (ch = wave id, 16 iters each); partials
// combined via padded LDS scratch. Staging / decode / zero-fill / output
// layout byte-identical to the proven round-1 kernel.

constexpr int Cc    = 64;
constexpr int Ww    = 33;
constexpr int HW    = 64 * Ww;        // 2112
constexpr int PLANE = Cc * HW;        // 135168
constexpr int TOT   = 16 * PLANE;     // 2162688 (elements in real half)
constexpr int WSTR  = Cc * 16 * 16;   // 16384: o-stride in weight tensor

#define CFMA(AR, AI, A, B, WRE, WIM)                                \
    AR.x = fmaf(A.x, WRE.x, AR.x); AR.x = fmaf(-B.x, WIM.x, AR.x); \
    AI.x = fmaf(A.x, WIM.x, AI.x); AI.x = fmaf( B.x, WRE.x, AI.x); \
    AR.y = fmaf(A.y, WRE.y, AR.y); AR.y = fmaf(-B.y, WIM.y, AR.y); \
    AI.y = fmaf(A.y, WIM.y, AI.y); AI.y = fmaf( B.y, WRE.y, AI.y); \
    AR.z = fmaf(A.z, WRE.z, AR.z); AR.z = fmaf(-B.z, WIM.z, AR.z); \
    AI.z = fmaf(A.z, WIM.z, AI.z); AI.z = fmaf( B.z, WRE.z, AI.z); \
    AR.w = fmaf(A.w, WRE.w, AR.w); AR.w = fmaf(-B.w, WIM.w, AR.w); \
    AI.w = fmaf(A.w, WIM.w, AI.w); AI.w = fmaf( B.w, WRE.w, AI.w);

__global__ __launch_bounds__(256) void spectral_fused_kernel(
    const float* __restrict__ xr, const float* __restrict__ xi,
    const float* __restrict__ wr1, const float* __restrict__ wi1,
    const float* __restrict__ wr2, const float* __restrict__ wi2,
    float* __restrict__ out)
{
    const int bid = blockIdx.x;
    const int t   = threadIdx.x;

    if (bid < 512) {
        // ---- compute blocks: oq(4) | blq(4) | xrow(16) | corner(2) ----
        const int oq     = bid & 3;
        const int blq    = (bid >> 2) & 3;
        const int xrow   = (bid >> 4) & 15;
        const int corner = bid >> 8;
        const int xin    = corner ? (48 + xrow) : xrow;
        const float* wr  = corner ? wr2 : wr1;
        const float* wi  = corner ? wi2 : wi1;

        // [r(2)][c(64)][blj(4)][y(16)] floats = 8192 floats = 32 KB
        __shared__ __align__(16) float xs[8192];

        // ---- stage x slice: identical to round-1 (proven) ----
        {
            const int y  = t & 15;
            const int wb = (t >> 4) & 3;
            const int cg = t >> 6;
            const int src_base = (blq * 4 + wb) * PLANE + xin * Ww + y;
            #pragma unroll
            for (int k = 0; k < 32; ++k) {
                const int r = k >> 4;
                const int c = ((k & 15) << 2) | cg;
                const float* src = (r ? xi : xr) + (size_t)src_base + c * HW;
                xs[r * 4096 + c * 64 + wb * 16 + y] = *src;
            }
        }
        __syncthreads();

        // ---- compute mapping: yq(2b) | bp(1b) | op(3b) | ch(2b=wave) ----
        const int yq = t & 3;              // y-quad
        const int bp = (t >> 2) & 1;       // bl-pair: blj = bp*2 + j
        const int op = (t >> 3) & 7;       // o-pair:  o = oq*16 + op*2 + i
        const int ch = t >> 6;             // c-chunk (wave-uniform)
        const int o0 = oq * 16 + op * 2;
        const int cb = ch * 16;

        const float* wrp = wr + o0 * WSTR + xrow * 16 + yq * 4;
        const float* wip = wi + o0 * WSTR + xrow * 16 + yq * 4;
        const float4* xsr = reinterpret_cast<const float4*>(xs) + bp * 8 + yq;
        const float4* xsi = xsr + 1024;    // imag half

        float4 ar[2][2], ai[2][2];
        #pragma unroll
        for (int i = 0; i < 2; ++i)
            #pragma unroll
            for (int j = 0; j < 2; ++j) {
                ar[i][j] = make_float4(0.f, 0.f, 0.f, 0.f);
                ai[i][j] = make_float4(0.f, 0.f, 0.f, 0.f);
            }

        #pragma unroll 4
        for (int cc = 0; cc < 16; ++cc) {
            const int c = cb + cc;
            float4 wre[2], wim[2], a[2], b[2];
            #pragma unroll
            for (int i = 0; i < 2; ++i) {
                wre[i] = *reinterpret_cast<const float4*>(wrp + i * WSTR + c * 256);
                wim[i] = *reinterpret_cast<const float4*>(wip + i * WSTR + c * 256);
            }
            #pragma unroll
            for (int j = 0; j < 2; ++j) {
                a[j] = xsr[c * 16 + j * 4];
                b[j] = xsi[c * 16 + j * 4];
            }
            CFMA(ar[0][0], ai[0][0], a[0], b[0], wre[0], wim[0])
            CFMA(ar[0][1], ai[0][1], a[1], b[1], wre[0], wim[0])
            CFMA(ar[1][0], ai[1][0], a[0], b[0], wre[1], wim[1])
            CFMA(ar[1][1], ai[1][1], a[1], b[1], wre[1], wim[1])
        }

        // ---- combine c-chunks: waves 1-3 park partials in LDS scratch ----
        __syncthreads();                   // all xs reads complete
        const int cfg = t & 63;
        if (ch) {
            // stride 9 float4 (144B) to break the 128B-stride bank pattern
            float4* sc = reinterpret_cast<float4*>(xs) + ((ch - 1) * 64 + cfg) * 9;
            #pragma unroll
            for (int i = 0; i < 2; ++i)
                #pragma unroll
                for (int j = 0; j < 2; ++j) {
                    sc[i * 2 + j]     = ar[i][j];
                    sc[4 + i * 2 + j] = ai[i][j];
                }
        }
        __syncthreads();
        if (!ch) {
            #pragma unroll
            for (int p = 0; p < 3; ++p) {
                const float4* sc = reinterpret_cast<const float4*>(xs)
                                 + ((p * 64 + cfg) * 9);
                #pragma unroll
                for (int i = 0; i < 2; ++i)
                    #pragma unroll
                    for (int j = 0; j < 2; ++j) {
                        const float4 pr = sc[i * 2 + j];
                        const float4 pi = sc[4 + i * 2 + j];
                        ar[i][j].x += pr.x; ar[i][j].y += pr.y;
                        ar[i][j].z += pr.z; ar[i][j].w += pr.w;
                        ai[i][j].x += pi.x; ai[i][j].y += pi.y;
                        ai[i][j].z += pi.z; ai[i][j].w += pi.w;
                    }
            }
            #pragma unroll
            for (int i = 0; i < 2; ++i)
                #pragma unroll
                for (int j = 0; j < 2; ++j) {
                    const int o  = o0 + i;
                    const int bl = blq * 4 + bp * 2 + j;
                    const size_t ob = (size_t)(bl * Cc + o) * HW
                                    + (size_t)xin * Ww + yq * 4;
                    out[ob + 0] = ar[i][j].x; out[ob + 1] = ar[i][j].y;
                    out[ob + 2] = ar[i][j].z; out[ob + 3] = ar[i][j].w;
                    out[TOT + ob + 0] = ai[i][j].x; out[TOT + ob + 1] = ai[i][j].y;
                    out[TOT + ob + 2] = ai[i][j].z; out[TOT + ob + 3] = ai[i][j].w;
                }
        }

        // ---- zero y in [16,33) tails: 16 o x 4 bl x 17 y x 2 ri = 2176 ----
        #pragma unroll
        for (int q = 0; q < 9; ++q) {
            const int k = t + q * 256;
            if (k < 2176) {
                const int ri   = k >= 1088;
                const int rem  = ri ? (k - 1088) : k;
                const int ol_  = rem / 68;            // local o (0..15)
                const int sub  = rem - ol_ * 68;      // 68 = 4 bl * 17 y
                const int blj_ = sub / 17;
                const int yy   = 16 + (sub - blj_ * 17);
                const size_t idx = (size_t)((blq * 4 + blj_) * Cc + oq * 16 + ol_) * HW
                                 + (size_t)xin * Ww + yy + (ri ? (size_t)TOT : 0);
                out[idx] = 0.f;
            }
        }
    } else {
        // ---- zero blocks: one per (ri, bl, o) plane, middle rows h in [16,48)
        // 1056 contiguous floats at plane*2112 + 528 -> 264 float4.
        const int p     = bid - 512;          // [0, 2048)
        const int ri    = p >> 10;
        const int plane = p & 1023;           // bl*64 + o
        float4* dst = (float4*)(out + (size_t)ri * TOT + (size_t)plane * HW + 528);
        const float4 z = make_float4(0.f, 0.f, 0.f, 0.f);
        dst[t] = z;
        if (t < 8) dst[256 + t] = z;          // 264 = 256 + 8
    }
}

extern "C" void kernel_launch(void* const* d_in, const int* in_sizes, int n_in,
                              void* d_out, int out_size, void* d_ws, size_t ws_size,
                              hipStream_t stream) {
    const float* xr  = (const float*)d_in[0];
    const float* xi  = (const float*)d_in[1];
    const float* wr1 = (const float*)d_in[2];
    const float* wi1 = (const float*)d_in[3];
    const float* wr2 = (const float*)d_in[4];
    const float* wi2 = (const float*)d_in[5];
    float* out = (float*)d_out;

    spectral_fused_kernel<<<2560, 256, 0, stream>>>(xr, xi, wr1, wi1, wr2, wi2, out);
}

// Round 7
// 93.885 us; speedup vs baseline: 1.2516x; 1.0064x over previous
//
#include <hip/hip_runtime.h>

// SpectralConv2d: B=2,L=8,C=64,H=64,W=33, M1=M2=16
// Round 7: cache-traffic reduction. Model: c-loop is L2/L3-BW bound,
// T = 16.8MB x (16/B_bl + 64/B_o) per pass. Round-1 (B_bl=4,B_o=16): 134MB.
// This kernel: B_bl=8, B_o=16 -> 101MB (weight refetch x4 -> x2).
//  - 256 compute blocks (corner2 x xrow16 x oq4 x blg2), 512 threads.
//  - x slice [r2][c64][bl8][y16] = 64KB LDS, staged once (32 loads/thr).
//  - thread = (yq4, bls4, ops8, ch4): 2o x 2bl x float4-y x 2ri tile,
//    c split 4-way (16 iters); per iter 4 global b128 + 4 ds b128 + 64 FMA.
//  - combine: partials parked in xs ([ch][k8][tile128] = 64KB exactly),
//    reduction + stores distributed over ALL 512 threads (round-6 fix);
//    every ds access is lane-consecutive float4 (conflict-free).
//  - zero-fill coverage identical to proven kernels: per-block y-tails
//    (16o x 8bl x 17y x 2ri), middle rows h in [16,48) via 1024 fill blocks.

constexpr int Cc    = 64;
constexpr int Ww    = 33;
constexpr int HW    = 64 * Ww;        // 2112
constexpr int PLANE = Cc * HW;        // 135168
constexpr int TOT   = 16 * PLANE;     // 2162688 (elements in real half)
constexpr int WSTR  = Cc * 16 * 16;   // 16384: o-stride in weight tensor

#define CFMA(AR, AI, A, B, WRE, WIM)                                \
    AR.x = fmaf(A.x, WRE.x, AR.x); AR.x = fmaf(-B.x, WIM.x, AR.x); \
    AI.x = fmaf(A.x, WIM.x, AI.x); AI.x = fmaf( B.x, WRE.x, AI.x); \
    AR.y = fmaf(A.y, WRE.y, AR.y); AR.y = fmaf(-B.y, WIM.y, AR.y); \
    AI.y = fmaf(A.y, WIM.y, AI.y); AI.y = fmaf( B.y, WRE.y, AI.y); \
    AR.z = fmaf(A.z, WRE.z, AR.z); AR.z = fmaf(-B.z, WIM.z, AR.z); \
    AI.z = fmaf(A.z, WIM.z, AI.z); AI.z = fmaf( B.z, WRE.z, AI.z); \
    AR.w = fmaf(A.w, WRE.w, AR.w); AR.w = fmaf(-B.w, WIM.w, AR.w); \
    AI.w = fmaf(A.w, WIM.w, AI.w); AI.w = fmaf( B.w, WRE.w, AI.w);

__global__ __launch_bounds__(512, 2) void spectral_fused_kernel(
    const float* __restrict__ xr, const float* __restrict__ xi,
    const float* __restrict__ wr1, const float* __restrict__ wi1,
    const float* __restrict__ wr2, const float* __restrict__ wi2,
    float* __restrict__ out)
{
    const int bid = blockIdx.x;
    const int t   = threadIdx.x;

    if (bid < 256) {
        // ---- compute blocks: oq(4) | blg(2) | xrow(16) | corner(2) ----
        const int oq     = bid & 3;
        const int blg    = (bid >> 2) & 1;     // 8-bl group
        const int xrow   = (bid >> 3) & 15;
        const int corner = bid >> 7;
        const int xin    = corner ? (48 + xrow) : xrow;
        const float* wr  = corner ? wr2 : wr1;
        const float* wi  = corner ? wi2 : wi1;

        // [r(2)][c(64)][bl(8)][y(16)] floats = 16384 floats = 64 KB
        __shared__ __align__(16) float xs[16384];

        // ---- stage x slice: 32 coalesced scalar loads per thread ----
        {
            const int y  = t & 15;
            const int wb = (t >> 4) & 7;       // bl within 8-group
            const int cg = t >> 7;             // 0..3
            const int src_base = (blg * 8 + wb) * PLANE + xin * Ww + y;
            #pragma unroll
            for (int k = 0; k < 32; ++k) {
                const int r = k >> 4;
                const int c = ((k & 15) << 2) | cg;
                const float* src = (r ? xi : xr) + (size_t)src_base + c * HW;
                xs[r * 8192 + c * 128 + wb * 16 + y] = *src;
            }
        }
        __syncthreads();

        // ---- compute: thread = yq(2b) | bls(2b) | ops(3b) | ch(2b) ----
        const int yq  = t & 3;
        const int bls = (t >> 2) & 3;          // bl-pair select (of 8)
        const int ops = (t >> 4) & 7;          // o-pair select (of 16)
        const int ch  = t >> 7;                // c-chunk
        const int o0  = oq * 16 + ops * 2;
        const int cb  = ch * 16;

        const float* wrp = wr + o0 * WSTR + xrow * 16 + yq * 4;
        const float* wip = wi + o0 * WSTR + xrow * 16 + yq * 4;
        const float4* xsr = reinterpret_cast<const float4*>(xs) + bls * 8 + yq;
        const float4* xsi = xsr + 2048;        // imag half (+8192 floats)

        float4 ar[2][2], ai[2][2];
        #pragma unroll
        for (int i = 0; i < 2; ++i)
            #pragma unroll
            for (int j = 0; j < 2; ++j) {
                ar[i][j] = make_float4(0.f, 0.f, 0.f, 0.f);
                ai[i][j] = make_float4(0.f, 0.f, 0.f, 0.f);
            }

        #pragma unroll 4
        for (int cc = 0; cc < 16; ++cc) {
            const int c = cb + cc;
            float4 wre[2], wim[2], a[2], b[2];
            #pragma unroll
            for (int i = 0; i < 2; ++i) {
                wre[i] = *reinterpret_cast<const float4*>(wrp + i * WSTR + c * 256);
                wim[i] = *reinterpret_cast<const float4*>(wip + i * WSTR + c * 256);
            }
            #pragma unroll
            for (int j = 0; j < 2; ++j) {
                a[j] = xsr[c * 32 + j * 4];
                b[j] = xsi[c * 32 + j * 4];
            }
            CFMA(ar[0][0], ai[0][0], a[0], b[0], wre[0], wim[0])
            CFMA(ar[0][1], ai[0][1], a[1], b[1], wre[0], wim[0])
            CFMA(ar[1][0], ai[1][0], a[0], b[0], wre[1], wim[1])
            CFMA(ar[1][1], ai[1][1], a[1], b[1], wre[1], wim[1])
        }

        // ---- park partials: sc[ch][k(8)][tile(128)] f4 = 64KB (reuse xs) ----
        __syncthreads();                        // all xs reads complete
        {
            float4* sc = reinterpret_cast<float4*>(xs);
            const int tile = t & 127;
            #pragma unroll
            for (int k2 = 0; k2 < 8; ++k2) {
                const int kk = k2 & 3;
                const int i  = kk >> 1, j = kk & 1;
                const float4 v = (k2 < 4) ? ar[i][j] : ai[i][j];
                sc[ch * 1024 + k2 * 128 + tile] = v;   // lane-consecutive
            }
        }
        __syncthreads();

        // ---- reduce + store: ALL 512 threads, 2 outputs each ----
        {
            const float4* sc = reinterpret_cast<const float4*>(xs);
            #pragma unroll
            for (int q = 0; q < 2; ++q) {
                const int m    = t + q * 512;   // [0,1024)
                const int tile = m & 127;
                const int k    = m >> 7;        // 0..7
                float4 acc = sc[k * 128 + tile];
                #pragma unroll
                for (int p = 1; p < 4; ++p) {
                    const float4 pr = sc[p * 1024 + k * 128 + tile];
                    acc.x += pr.x; acc.y += pr.y; acc.z += pr.z; acc.w += pr.w;
                }
                const int yq_  = tile & 3;
                const int bls_ = (tile >> 2) & 3;
                const int ops_ = (tile >> 4) & 7;
                const int ri   = k >> 2;
                const int kk   = k & 3;
                const int o    = oq * 16 + ops_ * 2 + (kk >> 1);
                const int bl   = blg * 8 + bls_ * 2 + (kk & 1);
                const size_t ob = (size_t)(bl * Cc + o) * HW
                                + (size_t)xin * Ww + yq_ * 4
                                + (ri ? (size_t)TOT : 0);
                out[ob + 0] = acc.x; out[ob + 1] = acc.y;
                out[ob + 2] = acc.z; out[ob + 3] = acc.w;
            }
        }

        // ---- zero y in [16,33) tails: 16o x 8bl x 17y x 2ri = 4352 ----
        #pragma unroll
        for (int q = 0; q < 9; ++q) {
            const int k = t + q * 512;
            if (k < 4352) {
                const int ri   = k >= 2176;
                const int rem  = ri ? (k - 2176) : k;
                const int ol_  = rem / 136;           // local o (0..15)
                const int sub  = rem - ol_ * 136;     // 136 = 8 bl * 17 y
                const int blj_ = sub / 17;
                const int yy   = 16 + (sub - blj_ * 17);
                const size_t idx = (size_t)((blg * 8 + blj_) * Cc + oq * 16 + ol_) * HW
                                 + (size_t)xin * Ww + yy + (ri ? (size_t)TOT : 0);
                out[idx] = 0.f;
            }
        }
    } else {
        // ---- zero blocks: 1024 blocks x 2 (ri,bl,o)-planes,
        //      middle rows h in [16,48): 264 float4 at plane*2112+528 ----
        const int p = bid - 256;                // [0, 1024)
        const float4 z = make_float4(0.f, 0.f, 0.f, 0.f);
        #pragma unroll
        for (int q = 0; q < 2; ++q) {
            const int j = t + q * 512;          // [0, 1024) covers 2x264=528
            if (j < 528) {
                const int pl  = p * 2 + (j >= 264);   // global plane [0,2048)
                const int off = j - (j >= 264 ? 264 : 0);
                const int ri  = pl >> 10;
                float4* dst = (float4*)(out + (size_t)ri * TOT
                                            + (size_t)(pl & 1023) * HW + 528);
                dst[off] = z;
            }
        }
    }
}

extern "C" void kernel_launch(void* const* d_in, const int* in_sizes, int n_in,
                              void* d_out, int out_size, void* d_ws, size_t ws_size,
                              hipStream_t stream) {
    const float* xr  = (const float*)d_in[0];
    const float* xi  = (const float*)d_in[1];
    const float* wr1 = (const float*)d_in[2];
    const float* wi1 = (const float*)d_in[3];
    const float* wr2 = (const float*)d_in[4];
    const float* wi2 = (const float*)d_in[5];
    float* out = (float*)d_out;

    spectral_fused_kernel<<<1280, 512, 0, stream>>>(xr, xi, wr1, wi1, wr2, wi2, out);
}